// Round 10
// baseline (350.376 us; speedup 1.0000x reference)
//
#include <hip/hip_runtime.h>

// ---------------------------------------------------------------------------
// RGAT 2-hop, N=100000, E=1600000, D=64, R=64.
// R10 = R9 + (a) build: counters at 128B stride (1 per L2 line; R9's 64B
// stride still paired counters on 128B lines), 2 edges/thread via int2
// loads, nontemporal csr stores. (b) hop: ungated 8-edge fast path while
// c+8 <= dmin(4 groups) -- no pad cndmasks, 8 gathers in flight; gated
// 4-edge tail (pe forced 0 before gather: unwritten csr slots are poison).
// Hop layout (R8/R9): 16-lane groups, 4 nodes/wave, lane = dim-quad;
// U,V packed bf16 ushort8 in LDS (1 ds_read_b128/edge, skew 136);
// dot via 4 DPP row_ror adds; agg dim-partitioned (no cross-lane reduce).
// ---------------------------------------------------------------------------

#define NEG_SLOPE 0.2f
#define CAP 64
#define DEGSTRIDE 32  // ints => 128 B per counter (one L2 line)

__device__ __forceinline__ float b2f_lo(unsigned x) {
    return __uint_as_float(x << 16);
}
__device__ __forceinline__ float b2f_hi(unsigned x) {
    return __uint_as_float(x & 0xffff0000u);
}
__device__ __forceinline__ unsigned short f2b(float x) {  // RNE
    unsigned u = __float_as_uint(x);
    unsigned r = u + 0x7fffu + ((u >> 16) & 1u);
    return (unsigned short)(r >> 16);
}

// sum over the 16 lanes of a row-group; result in ALL 16 lanes. VALU pipe.
__device__ __forceinline__ float ror_sum16(float x) {
#define ROR_ADD(ctrl)                                                          \
    x += __int_as_float(                                                       \
        __builtin_amdgcn_update_dpp(0, __float_as_int(x), ctrl, 0xf, 0xf, true))
    ROR_ADD(0x121);  // row_ror:1
    ROR_ADD(0x122);  // row_ror:2
    ROR_ADD(0x124);  // row_ror:4
    ROR_ADD(0x128);  // row_ror:8
#undef ROR_ADD
    return x;
}

// Wuvb packed bf16: for (r, half, d): pos = r*128 + (d>>2)*8 + half*4 + (d&3)
// i.e. per (r, dim-quad s): 8 ushorts [U0..U3 | V0..V3].
__global__ void proj_kernel(const float* __restrict__ W,
                            const float* __restrict__ rel,
                            unsigned short* __restrict__ Wuvb) {
    int r = blockIdx.x;
    int i = threadIdx.x;  // 0..127: i<64 -> U row i, i>=64 -> V row i-64
    __shared__ float rels[64];
    if (i < 64) rels[i] = rel[r * 64 + i];
    __syncthreads();
    float s = 0.f;
#pragma unroll
    for (int j = 0; j < 64; ++j) s += W[i * 64 + j] * rels[j];
    int d = i & 63, half = i >> 6;
    Wuvb[r * 128 + (d >> 2) * 8 + half * 4 + (d & 3)] = f2b(s);
}

// fp32 -> bf16 cast (float4 -> ushort4), n4 = total/4
__global__ __launch_bounds__(256) void cast_kernel(
    const float* __restrict__ src, unsigned short* __restrict__ dst, int n4) {
    int i = blockIdx.x * 256 + threadIdx.x;
    if (i >= n4) return;
    float4 v = *(const float4*)(src + (long)i * 4);
    ushort4 o = {f2b(v.x), f2b(v.y), f2b(v.z), f2b(v.w)};
    *(ushort4*)(dst + (long)i * 4) = o;
}

// ---------------- one-pass CSR build ----------------
// 2 edges per thread; counters one per 128B line; nontemporal entry stores.
__global__ __launch_bounds__(256) void build_kernel(
    const int* __restrict__ head, const int* __restrict__ tail,
    const int* __restrict__ etype, int* __restrict__ deg,
    int* __restrict__ csr, int E) {
    int i = blockIdx.x * 256 + threadIdx.x;
    int e0 = i * 2, e1 = e0 + 1;
    if (e1 < E) {
        int2 h2 = *(const int2*)(head + e0);
        int2 t2 = *(const int2*)(tail + e0);
        int2 r2 = *(const int2*)(etype + e0);
        int c0 = atomicAdd(deg + (long)h2.x * DEGSTRIDE, 1);
        int c1 = atomicAdd(deg + (long)h2.y * DEGSTRIDE, 1);
        if (c0 < CAP)
            __builtin_nontemporal_store((t2.x << 6) | r2.x,
                                        csr + (long)h2.x * CAP + c0);
        if (c1 < CAP)
            __builtin_nontemporal_store((t2.y << 6) | r2.y,
                                        csr + (long)h2.y * CAP + c1);
    } else if (e0 < E) {
        int h = head[e0];
        int c = atomicAdd(deg + (long)h * DEGSTRIDE, 1);
        if (c < CAP)
            __builtin_nontemporal_store((tail[e0] << 6) | etype[e0],
                                        csr + (long)h * CAP + c);
    }
}

// ---------------- fused hop (16-lane groups) ----------------
// 512 threads = 8 waves = 32 nodes per block. Group = 16 lanes = 1 node,
// lane s owns dims 4s..4s+3.
__global__ __launch_bounds__(512) void hop_kernel(
    const int* __restrict__ deg16, const int* __restrict__ csr,
    const unsigned short* __restrict__ Wuvb,
    const unsigned short* __restrict__ embb, const float* res_prev,
    unsigned short* embb_out, float* res_out, int N) {
    __shared__ unsigned short sUV[64 * 136];  // 17 KB, skewed stride
    for (int k = threadIdx.x; k < 64 * 128; k += 512) {
        int r = k >> 7, q = k & 127;
        sUV[r * 136 + q] = Wuvb[k];
    }
    __syncthreads();

    int tid = threadIdx.x;
    int s = tid & 15;
    int node = blockIdx.x * 32 + (tid >> 4);
    bool valid = node < N;
    long nb64 = (long)node * 64;

    uint2 hdp = valid ? *(const uint2*)(embb + nb64 + s * 4)
                      : make_uint2(0u, 0u);
    float hd0 = b2f_lo(hdp.x), hd1 = b2f_hi(hdp.x);
    float hd2 = b2f_lo(hdp.y), hd3 = b2f_hi(hdp.y);

    int deg = valid ? min(deg16[(long)node * DEGSTRIDE], CAP) : 0;
    int r0 = node * CAP;
    // wave-uniform min/max degree over the wave's 4 groups
    int dmin = min(min(__shfl(deg, 0), __shfl(deg, 16)),
                   min(__shfl(deg, 32), __shfl(deg, 48)));
    int dmax = max(max(__shfl(deg, 0), __shfl(deg, 16)),
                   max(__shfl(deg, 32), __shfl(deg, 48)));

    float a0 = 0.f, a1 = 0.f, a2 = 0.f, a3 = 0.f, l = 0.f;

    auto edge_body = [&](int pe, uint2 rw, bool gated, int idx) {
        int rr = pe & 63;
        uint4 uv = *(const uint4*)(sUV + rr * 136 + s * 8);
        float U0 = b2f_lo(uv.x), U1 = b2f_hi(uv.x);
        float U2 = b2f_lo(uv.y), U3 = b2f_hi(uv.y);
        float V0 = b2f_lo(uv.z), V1 = b2f_hi(uv.z);
        float V2 = b2f_lo(uv.w), V3 = b2f_hi(uv.w);
        float e0 = b2f_lo(rw.x), e1 = b2f_hi(rw.x);
        float e2 = b2f_lo(rw.y), e3 = b2f_hi(rw.y);
        float sd = hd0 * U0 + hd1 * U1 + hd2 * U2 + hd3 * U3 +
                   e0 * V0 + e1 * V1 + e2 * V2 + e3 * V3;
        sd = ror_sum16(sd);                   // 64-dot in all 16 lanes
        float p = fmaxf(sd, NEG_SLOPE * sd);  // leaky (slope<1)
        float w = __expf(p);
        if (gated) w = (idx < deg) ? w : 0.f;
        l += w;
        a0 += w * e0; a1 += w * e1; a2 += w * e2; a3 += w * e3;
    };

    int c = 0;
    // fast path: 8 edges/iter, all groups full, no gating
    for (; c + 8 <= dmin; c += 8) {
        uint4 ea = *(const uint4*)(csr + r0 + c);
        uint4 eb = *(const uint4*)(csr + r0 + c + 4);
        int pe[8] = {(int)ea.x, (int)ea.y, (int)ea.z, (int)ea.w,
                     (int)eb.x, (int)eb.y, (int)eb.z, (int)eb.w};
        uint2 rw[8];
#pragma unroll
        for (int u = 0; u < 8; ++u)
            rw[u] = *(const uint2*)(embb + (long)(pe[u] >> 6) * 64 + s * 4);
#pragma unroll
        for (int u = 0; u < 8; ++u) edge_body(pe[u], rw[u], false, 0);
    }
    // gated tail: 4 edges/iter; pe forced 0 before gather (poison safety)
    for (; c < dmax; c += 4) {
        uint4 e4 = *(const uint4*)(csr + r0 + c);
        int pe[4];
        pe[0] = (c + 0 < deg) ? (int)e4.x : 0;
        pe[1] = (c + 1 < deg) ? (int)e4.y : 0;
        pe[2] = (c + 2 < deg) ? (int)e4.z : 0;
        pe[3] = (c + 3 < deg) ? (int)e4.w : 0;
        uint2 rw[4];
#pragma unroll
        for (int u = 0; u < 4; ++u)
            rw[u] = *(const uint2*)(embb + (long)(pe[u] >> 6) * 64 + s * 4);
#pragma unroll
        for (int u = 0; u < 4; ++u) edge_body(pe[u], rw[u], true, c + u);
    }

    if (valid) {
        float inv = (l > 0.f) ? 1.f / l : 0.f;
        float v0 = hd0 + a0 * inv, v1 = hd1 + a1 * inv;
        float v2 = hd2 + a2 * inv, v3 = hd3 + a3 * inv;
        float sq = v0 * v0 + v1 * v1 + v2 * v2 + v3 * v3;
        sq = ror_sum16(sq);                       // group-uniform
        float rn = 1.f / fmaxf(sqrtf(sq), 1e-12f);
        v0 *= rn; v1 *= rn; v2 *= rn; v3 *= rn;
        if (embb_out) {
            ushort4 o = {f2b(v0), f2b(v1), f2b(v2), f2b(v3)};
            *(ushort4*)(embb_out + nb64 + s * 4) = o;
        }
        float4 rp = *(const float4*)(res_prev + nb64 + s * 4);
        float4 ro = {0.5f * rp.x + v0, 0.5f * rp.y + v1,
                     0.5f * rp.z + v2, 0.5f * rp.w + v3};
        *(float4*)(res_out + nb64 + s * 4) = ro;
    }
}

extern "C" void kernel_launch(void* const* d_in, const int* in_sizes, int n_in,
                              void* d_out, int out_size, void* d_ws, size_t ws_size,
                              hipStream_t stream) {
    const int*   edge_index = (const int*)d_in[0];   // [2, E]
    const int*   etype      = (const int*)d_in[1];   // [E]
    const float* ent        = (const float*)d_in[2]; // [N, 64]
    const float* rel        = (const float*)d_in[3]; // [R, 64]
    const float* W          = (const float*)d_in[4]; // [128, 64]

    const int E = in_sizes[1];
    const int N = in_sizes[2] / 64;
    const int R = in_sizes[3] / 64;
    const int* head = edge_index;
    const int* tail = edge_index + E;
    float* out = (float*)d_out;

    // workspace layout
    char* w = (char*)d_ws;
    unsigned short* Wuvb = (unsigned short*)w;  w += (size_t)R * 128 * 2;
    int* deg = (int*)w;                         w += (size_t)N * DEGSTRIDE * 4;
    int* csr = (int*)w;                         w += (size_t)N * CAP * 4;
    unsigned short* entb = (unsigned short*)w;  w += (size_t)N * 64 * 2;
    unsigned short* emb1b = (unsigned short*)w; w += (size_t)N * 64 * 2;

    const int bb = ((E + 1) / 2 + 255) / 256;
    const int hb = (N + 31) / 32;
    const int cb = (N * 16 + 255) / 256;  // cast: N*64/4 float4s

    proj_kernel<<<R, 128, 0, stream>>>(W, rel, Wuvb);
    cast_kernel<<<cb, 256, 0, stream>>>(ent, entb, N * 16);

    // one-pass CSR build (graph constant across hops)
    hipMemsetAsync(deg, 0, (size_t)N * DEGSTRIDE * 4, stream);
    build_kernel<<<bb, 256, 0, stream>>>(head, tail, etype, deg, csr, E);

    // hop 1
    hop_kernel<<<hb, 512, 0, stream>>>(deg, csr, Wuvb, entb, ent, emb1b, out, N);
    // hop 2 (res in place)
    hop_kernel<<<hb, 512, 0, stream>>>(deg, csr, Wuvb, emb1b, out, nullptr, out, N);
}

// Round 11
// 307.517 us; speedup vs baseline: 1.1394x; 1.1394x over previous
//
#include <hip/hip_runtime.h>

// ---------------------------------------------------------------------------
// RGAT 2-hop, N=100000, E=1600000, D=64, R=64.
// R11 = R10 with build regressions reverted: 1 edge/thread (full MLP),
// plain L2 stores (nontemporal defeated write-combining), keeping the one
// good change: DEGSTRIDE=32 -> one counter per 128 B L2 line.
// Hop (unchanged from R10): 16-lane groups, 4 nodes/wave, lane = dim-quad;
// U,V packed bf16 ushort8 in LDS (1 ds_read_b128/edge, skew 136); dot via
// 4 DPP row_ror adds; ungated 8-edge fast path to dmin + gated 4-edge tail
// (pe forced 0 before gather: unwritten csr slots are poison).
// ---------------------------------------------------------------------------

#define NEG_SLOPE 0.2f
#define CAP 64
#define DEGSTRIDE 32  // ints => 128 B per counter (one L2 line)

__device__ __forceinline__ float b2f_lo(unsigned x) {
    return __uint_as_float(x << 16);
}
__device__ __forceinline__ float b2f_hi(unsigned x) {
    return __uint_as_float(x & 0xffff0000u);
}
__device__ __forceinline__ unsigned short f2b(float x) {  // RNE
    unsigned u = __float_as_uint(x);
    unsigned r = u + 0x7fffu + ((u >> 16) & 1u);
    return (unsigned short)(r >> 16);
}

// sum over the 16 lanes of a row-group; result in ALL 16 lanes. VALU pipe.
__device__ __forceinline__ float ror_sum16(float x) {
#define ROR_ADD(ctrl)                                                          \
    x += __int_as_float(                                                       \
        __builtin_amdgcn_update_dpp(0, __float_as_int(x), ctrl, 0xf, 0xf, true))
    ROR_ADD(0x121);  // row_ror:1
    ROR_ADD(0x122);  // row_ror:2
    ROR_ADD(0x124);  // row_ror:4
    ROR_ADD(0x128);  // row_ror:8
#undef ROR_ADD
    return x;
}

// Wuvb packed bf16: for (r, half, d): pos = r*128 + (d>>2)*8 + half*4 + (d&3)
// i.e. per (r, dim-quad s): 8 ushorts [U0..U3 | V0..V3].
__global__ void proj_kernel(const float* __restrict__ W,
                            const float* __restrict__ rel,
                            unsigned short* __restrict__ Wuvb) {
    int r = blockIdx.x;
    int i = threadIdx.x;  // 0..127: i<64 -> U row i, i>=64 -> V row i-64
    __shared__ float rels[64];
    if (i < 64) rels[i] = rel[r * 64 + i];
    __syncthreads();
    float s = 0.f;
#pragma unroll
    for (int j = 0; j < 64; ++j) s += W[i * 64 + j] * rels[j];
    int d = i & 63, half = i >> 6;
    Wuvb[r * 128 + (d >> 2) * 8 + half * 4 + (d & 3)] = f2b(s);
}

// fp32 -> bf16 cast (float4 -> ushort4), n4 = total/4
__global__ __launch_bounds__(256) void cast_kernel(
    const float* __restrict__ src, unsigned short* __restrict__ dst, int n4) {
    int i = blockIdx.x * 256 + threadIdx.x;
    if (i >= n4) return;
    float4 v = *(const float4*)(src + (long)i * 4);
    ushort4 o = {f2b(v.x), f2b(v.y), f2b(v.z), f2b(v.w)};
    *(ushort4*)(dst + (long)i * 4) = o;
}

// ---------------- one-pass CSR build ----------------
// 1 edge/thread, counters one per 128B line, plain stores (L2 combining).
__global__ __launch_bounds__(256) void build_kernel(
    const int* __restrict__ head, const int* __restrict__ tail,
    const int* __restrict__ etype, int* __restrict__ deg,
    int* __restrict__ csr, int E) {
    int i = blockIdx.x * 256 + threadIdx.x;
    if (i >= E) return;
    int h = head[i];
    int entry = (tail[i] << 6) | etype[i];  // ready before atomic returns
    int c = atomicAdd(deg + (long)h * DEGSTRIDE, 1);
    if (c < CAP) csr[(long)h * CAP + c] = entry;
}

// ---------------- fused hop (16-lane groups) ----------------
// 512 threads = 8 waves = 32 nodes per block. Group = 16 lanes = 1 node,
// lane s owns dims 4s..4s+3.
__global__ __launch_bounds__(512) void hop_kernel(
    const int* __restrict__ deg16, const int* __restrict__ csr,
    const unsigned short* __restrict__ Wuvb,
    const unsigned short* __restrict__ embb, const float* res_prev,
    unsigned short* embb_out, float* res_out, int N) {
    __shared__ unsigned short sUV[64 * 136];  // 17 KB, skewed stride
    for (int k = threadIdx.x; k < 64 * 128; k += 512) {
        int r = k >> 7, q = k & 127;
        sUV[r * 136 + q] = Wuvb[k];
    }
    __syncthreads();

    int tid = threadIdx.x;
    int s = tid & 15;
    int node = blockIdx.x * 32 + (tid >> 4);
    bool valid = node < N;
    long nb64 = (long)node * 64;

    uint2 hdp = valid ? *(const uint2*)(embb + nb64 + s * 4)
                      : make_uint2(0u, 0u);
    float hd0 = b2f_lo(hdp.x), hd1 = b2f_hi(hdp.x);
    float hd2 = b2f_lo(hdp.y), hd3 = b2f_hi(hdp.y);

    int deg = valid ? min(deg16[(long)node * DEGSTRIDE], CAP) : 0;
    int r0 = node * CAP;
    // wave-uniform min/max degree over the wave's 4 groups
    int dmin = min(min(__shfl(deg, 0), __shfl(deg, 16)),
                   min(__shfl(deg, 32), __shfl(deg, 48)));
    int dmax = max(max(__shfl(deg, 0), __shfl(deg, 16)),
                   max(__shfl(deg, 32), __shfl(deg, 48)));

    float a0 = 0.f, a1 = 0.f, a2 = 0.f, a3 = 0.f, l = 0.f;

    auto edge_body = [&](int pe, uint2 rw, bool gated, int idx) {
        int rr = pe & 63;
        uint4 uv = *(const uint4*)(sUV + rr * 136 + s * 8);
        float U0 = b2f_lo(uv.x), U1 = b2f_hi(uv.x);
        float U2 = b2f_lo(uv.y), U3 = b2f_hi(uv.y);
        float V0 = b2f_lo(uv.z), V1 = b2f_hi(uv.z);
        float V2 = b2f_lo(uv.w), V3 = b2f_hi(uv.w);
        float e0 = b2f_lo(rw.x), e1 = b2f_hi(rw.x);
        float e2 = b2f_lo(rw.y), e3 = b2f_hi(rw.y);
        float sd = hd0 * U0 + hd1 * U1 + hd2 * U2 + hd3 * U3 +
                   e0 * V0 + e1 * V1 + e2 * V2 + e3 * V3;
        sd = ror_sum16(sd);                   // 64-dot in all 16 lanes
        float p = fmaxf(sd, NEG_SLOPE * sd);  // leaky (slope<1)
        float w = __expf(p);
        if (gated) w = (idx < deg) ? w : 0.f;
        l += w;
        a0 += w * e0; a1 += w * e1; a2 += w * e2; a3 += w * e3;
    };

    int c = 0;
    // fast path: 8 edges/iter, all groups full, no gating
    for (; c + 8 <= dmin; c += 8) {
        uint4 ea = *(const uint4*)(csr + r0 + c);
        uint4 eb = *(const uint4*)(csr + r0 + c + 4);
        int pe[8] = {(int)ea.x, (int)ea.y, (int)ea.z, (int)ea.w,
                     (int)eb.x, (int)eb.y, (int)eb.z, (int)eb.w};
        uint2 rw[8];
#pragma unroll
        for (int u = 0; u < 8; ++u)
            rw[u] = *(const uint2*)(embb + (long)(pe[u] >> 6) * 64 + s * 4);
#pragma unroll
        for (int u = 0; u < 8; ++u) edge_body(pe[u], rw[u], false, 0);
    }
    // gated tail: 4 edges/iter; pe forced 0 before gather (poison safety)
    for (; c < dmax; c += 4) {
        uint4 e4 = *(const uint4*)(csr + r0 + c);
        int pe[4];
        pe[0] = (c + 0 < deg) ? (int)e4.x : 0;
        pe[1] = (c + 1 < deg) ? (int)e4.y : 0;
        pe[2] = (c + 2 < deg) ? (int)e4.z : 0;
        pe[3] = (c + 3 < deg) ? (int)e4.w : 0;
        uint2 rw[4];
#pragma unroll
        for (int u = 0; u < 4; ++u)
            rw[u] = *(const uint2*)(embb + (long)(pe[u] >> 6) * 64 + s * 4);
#pragma unroll
        for (int u = 0; u < 4; ++u) edge_body(pe[u], rw[u], true, c + u);
    }

    if (valid) {
        float inv = (l > 0.f) ? 1.f / l : 0.f;
        float v0 = hd0 + a0 * inv, v1 = hd1 + a1 * inv;
        float v2 = hd2 + a2 * inv, v3 = hd3 + a3 * inv;
        float sq = v0 * v0 + v1 * v1 + v2 * v2 + v3 * v3;
        sq = ror_sum16(sq);                       // group-uniform
        float rn = 1.f / fmaxf(sqrtf(sq), 1e-12f);
        v0 *= rn; v1 *= rn; v2 *= rn; v3 *= rn;
        if (embb_out) {
            ushort4 o = {f2b(v0), f2b(v1), f2b(v2), f2b(v3)};
            *(ushort4*)(embb_out + nb64 + s * 4) = o;
        }
        float4 rp = *(const float4*)(res_prev + nb64 + s * 4);
        float4 ro = {0.5f * rp.x + v0, 0.5f * rp.y + v1,
                     0.5f * rp.z + v2, 0.5f * rp.w + v3};
        *(float4*)(res_out + nb64 + s * 4) = ro;
    }
}

extern "C" void kernel_launch(void* const* d_in, const int* in_sizes, int n_in,
                              void* d_out, int out_size, void* d_ws, size_t ws_size,
                              hipStream_t stream) {
    const int*   edge_index = (const int*)d_in[0];   // [2, E]
    const int*   etype      = (const int*)d_in[1];   // [E]
    const float* ent        = (const float*)d_in[2]; // [N, 64]
    const float* rel        = (const float*)d_in[3]; // [R, 64]
    const float* W          = (const float*)d_in[4]; // [128, 64]

    const int E = in_sizes[1];
    const int N = in_sizes[2] / 64;
    const int R = in_sizes[3] / 64;
    const int* head = edge_index;
    const int* tail = edge_index + E;
    float* out = (float*)d_out;

    // workspace layout
    char* w = (char*)d_ws;
    unsigned short* Wuvb = (unsigned short*)w;  w += (size_t)R * 128 * 2;
    int* deg = (int*)w;                         w += (size_t)N * DEGSTRIDE * 4;
    int* csr = (int*)w;                         w += (size_t)N * CAP * 4;
    unsigned short* entb = (unsigned short*)w;  w += (size_t)N * 64 * 2;
    unsigned short* emb1b = (unsigned short*)w; w += (size_t)N * 64 * 2;

    const int eb = (E + 255) / 256;
    const int hb = (N + 31) / 32;
    const int cb = (N * 16 + 255) / 256;  // cast: N*64/4 float4s

    proj_kernel<<<R, 128, 0, stream>>>(W, rel, Wuvb);
    cast_kernel<<<cb, 256, 0, stream>>>(ent, entb, N * 16);

    // one-pass CSR build (graph constant across hops)
    hipMemsetAsync(deg, 0, (size_t)N * DEGSTRIDE * 4, stream);
    build_kernel<<<eb, 256, 0, stream>>>(head, tail, etype, deg, csr, E);

    // hop 1
    hop_kernel<<<hb, 512, 0, stream>>>(deg, csr, Wuvb, entb, ent, emb1b, out, N);
    // hop 2 (res in place)
    hop_kernel<<<hb, 512, 0, stream>>>(deg, csr, Wuvb, emb1b, out, nullptr, out, N);
}